// Round 1
// baseline (9759.027 us; speedup 1.0000x reference)
//
#include <hip/hip_runtime.h>
#include <hip/hip_fp16.h>

#define SCAN_T 256
#define DELTA 128          // rows per bucket (block owns one bucket)
#define LOG_DELTA 7
#define CAP 5120           // slab capacity per bucket (mean 4096, +16 sigma)
#define PA_CHUNK 8192      // edges per pass-A block
#define MAXB 2048          // >= number of buckets (1563)
#define NSB 1024           // col sort bins (col>>8 -> 0..781)
#define SORT_SHIFT 8
#define ACCS 65            // LDS accumulator row stride in floats (padded: bank=(r+2l)%32)

typedef unsigned long long u64;

// ---------------- logmap0 on the hyperboloid (c = 1), fp16 output ----------
// half-wave (32 lanes) per row; lane l owns dims (2l, 2l+1)
__global__ void compute_h_kernel(const float* __restrict__ x, __half2* __restrict__ h, int N) {
    int hw = (blockIdx.x * blockDim.x + threadIdx.x) >> 5;
    if (hw >= N) return;
    int l = threadIdx.x & 31;
    const float2* x2 = (const float2*)x;
    float2 v = x2[hw * 32 + l];
    float y2 = (l == 0) ? v.y * v.y : v.x * v.x + v.y * v.y;
    #pragma unroll
    for (int m = 16; m >= 1; m >>= 1) y2 += __shfl_xor(y2, m, 32);
    float x0 = __shfl(v.x, 0, 32);
    float ynorm = fmaxf(sqrtf(y2), 1e-15f);
    float theta = fmaxf(x0, 1.0f + 1e-7f);
    float alpha = acoshf(theta) / ynorm;
    float2 r = (l == 0) ? make_float2(0.0f, v.y * alpha)
                        : make_float2(v.x * alpha, v.y * alpha);
    h[hw * 32 + l] = __float22half2_rn(r);
}

__device__ __forceinline__ int block_incl_scan(int x) { // 256 threads
    __shared__ int sh[SCAN_T];
    int t = threadIdx.x;
    sh[t] = x; __syncthreads();
    for (int ofs = 1; ofs < SCAN_T; ofs <<= 1) {
        int y = (t >= ofs) ? sh[t - ofs] : 0;
        __syncthreads();
        x += y; sh[t] = x;
        __syncthreads();
    }
    return x;
}

// ---------------- Pass A: bin edges into row-buckets, block-private runs ----
// slab slot: [63:50]=local row (7b), [49:32]=col (18b), [31:0]=val f32 bits
__global__ void pass_a_kernel(const int* __restrict__ rows, const int* __restrict__ cols,
                              const float* __restrict__ vals, int* __restrict__ fill,
                              u64* __restrict__ slab, int nnz, int NB) {
    __shared__ int cnt[MAXB];
    __shared__ int cur[MAXB];
    int t = threadIdx.x;
    int start = blockIdx.x * PA_CHUNK;
    int end = min(start + PA_CHUNK, nnz);
    for (int i = t; i < NB; i += 256) cnt[i] = 0;
    __syncthreads();
    for (int e = start + t; e < end; e += 256)
        atomicAdd(&cnt[rows[e] >> LOG_DELTA], 1);
    __syncthreads();
    for (int i = t; i < NB; i += 256) {
        int c = cnt[i];
        cur[i] = (c > 0) ? atomicAdd(&fill[i], c) : 0;
    }
    __syncthreads();
    for (int e = start + t; e < end; e += 256) {
        int r = rows[e];
        int bkt = r >> LOG_DELTA;
        int lr = r & (DELTA - 1);
        int pos = atomicAdd(&cur[bkt], 1);
        if (pos < CAP) {
            u64 hi = ((u64)(((unsigned)lr << 18) | (unsigned)cols[e])) << 32;
            slab[(size_t)bkt * CAP + pos] = hi | (u64)__float_as_uint(vals[e]);
        }
    }
}

// ---------------- bucket-count exclusive scan (one block) ------------------
__global__ void bucket_scan_kernel(const int* __restrict__ fill, int* __restrict__ csr_base,
                                   int NB, int nnz) {
    int t = threadIdx.x;
    int a[8]; int s = 0;
    #pragma unroll
    for (int k = 0; k < 8; ++k) {
        int i = t * 8 + k;
        a[k] = (i < NB) ? fill[i] : 0;
        s += a[k];
    }
    int incl = block_incl_scan(s);
    int run = incl - s;
    #pragma unroll
    for (int k = 0; k < 8; ++k) {
        int i = t * 8 + k;
        if (i < NB) csr_base[i] = run;
        run += a[k];
    }
    if (t == 0) csr_base[NB] = nnz;
}

// ---------------- Pass B: per-bucket count-sort by column band -------------
// Sorts each bucket's edges purely by col>>SORT_SHIFT so the whole block
// sweeps col space monotonically -> co-resident blocks' gathers cluster in an
// L2-resident moving band. final edge: [63:32]=val f32 bits, [24:18]=lrow, [17:0]=col
__global__ void pass_b_kernel(const int* __restrict__ fill, const u64* __restrict__ slab,
                              const int* __restrict__ csr_base, u64* __restrict__ edges) {
    __shared__ int bins[NSB];   // 4 KB
    int b = blockIdx.x;
    int t = threadIdx.x;
    for (int i = t; i < NSB; i += 256) bins[i] = 0;
    __syncthreads();
    int m = fill[b];
    if (m > CAP) m = CAP;
    const u64* sl = slab + (size_t)b * CAP;
    for (int e = t; e < m; e += 256) {
        u64 u = sl[e];
        int col = (int)((u >> 32) & 0x3FFFFu);
        atomicAdd(&bins[col >> SORT_SHIFT], 1);
    }
    __syncthreads();
    int base = t * 4;
    int s = 0;
    #pragma unroll
    for (int k = 0; k < 4; ++k) s += bins[base + k];
    int incl = block_incl_scan(s);
    int run = incl - s;
    #pragma unroll
    for (int k = 0; k < 4; ++k) { int c = bins[base + k]; bins[base + k] = run; run += c; }
    __syncthreads();
    int cb = csr_base[b];
    for (int e = t; e < m; e += 256) {
        u64 u = sl[e];
        int lr = (int)(u >> 50);
        unsigned col = (unsigned)(u >> 32) & 0x3FFFFu;
        unsigned vb = (unsigned)u;
        int pos = cb + atomicAdd(&bins[(int)(col >> SORT_SHIFT)], 1);
        edges[pos] = ((u64)vb << 32) | ((u64)(unsigned)lr << 18) | (u64)col;
    }
}

// ---------------- phase-major SpMM: LDS fp32 accumulators ------------------
// Block owns bucket b (128 rows). 8 half-waves each stream 8 consecutive
// col-sorted edges per iteration; lane l owns dims (2l, 2l+1) of the gathered
// pin row; products land in LDS via ds_add_f32 (stride 65 pads banks).
__device__ __forceinline__ void bucket_accumulate(float* __restrict__ acc,
        const int* __restrict__ csr_base, const u64* __restrict__ edges,
        const __half2* __restrict__ pin) {
    int b = blockIdx.x, t = threadIdx.x, sub = t >> 5, l = t & 31;
    for (int i = t; i < DELTA * ACCS; i += 256) acc[i] = 0.0f;
    __syncthreads();
    int start = csr_base[b], end = csr_base[b + 1];
    int l2 = 2 * l;
    int base = start;
    for (; base + 64 <= end; base += 64) {
        int e = base + sub * 8;
        u64 E[8];
        #pragma unroll
        for (int k = 0; k < 8; ++k) E[k] = __builtin_nontemporal_load(&edges[e + k]);
        float vx[8], vy[8]; int R[8];
        #pragma unroll
        for (int k = 0; k < 8; ++k) {
            int c = (int)(E[k] & 0x3FFFFu);
            R[k] = (int)((E[k] >> 18) & 0x7Fu);
            float v = __int_as_float((int)(E[k] >> 32));
            float2 f = __half22float2(pin[c * 32 + l]);
            vx[k] = v * f.x; vy[k] = v * f.y;
        }
        #pragma unroll
        for (int k = 0; k < 8; ++k) {
            atomicAdd(&acc[R[k] * ACCS + l2], vx[k]);
            atomicAdd(&acc[R[k] * ACCS + l2 + 1], vy[k]);
        }
    }
    for (int e = base + sub; e < end; e += 8) {
        u64 u = __builtin_nontemporal_load(&edges[e]);
        int c = (int)(u & 0x3FFFFu);
        int r = (int)((u >> 18) & 0x7Fu);
        float v = __int_as_float((int)(u >> 32));
        float2 f = __half22float2(pin[c * 32 + l]);
        atomicAdd(&acc[r * ACCS + l2], v * f.x);
        atomicAdd(&acc[r * ACCS + l2 + 1], v * f.y);
    }
    __syncthreads();
}

__global__ __launch_bounds__(256, 4)
void spmm_acc_kernel(const int* __restrict__ csr_base, const u64* __restrict__ edges,
                     const __half2* __restrict__ pin, __half2* __restrict__ pout, int N) {
    __shared__ float acc[DELTA * ACCS];   // 33,280 B -> 4 blocks/CU
    bucket_accumulate(acc, csr_base, edges, pin);
    int t = threadIdx.x, sub = t >> 5, l = t & 31;
    int row0 = blockIdx.x * DELTA;
    for (int r = sub; r < DELTA; r += 8) {
        int row = row0 + r;
        if (row < N) {
            float2 f = make_float2(acc[r * ACCS + 2 * l], acc[r * ACCS + 2 * l + 1]);
            pout[row * 32 + l] = __float22half2_rn(f);
        }
    }
}

// final: acc = A*p3 (=p4);  out = 4*p1 + 5*p2 + 3*p3 + acc
__global__ __launch_bounds__(256, 4)
void spmm_acc_final_kernel(const int* __restrict__ csr_base, const u64* __restrict__ edges,
                           const __half2* __restrict__ p1, const __half2* __restrict__ p2,
                           const __half2* __restrict__ p3, float2* __restrict__ out, int N) {
    __shared__ float acc[DELTA * ACCS];
    bucket_accumulate(acc, csr_base, edges, p3);
    int t = threadIdx.x, sub = t >> 5, l = t & 31;
    int row0 = blockIdx.x * DELTA;
    for (int r = sub; r < DELTA; r += 8) {
        int row = row0 + r;
        if (row < N) {
            int idx = row * 32 + l;
            float2 f1 = __half22float2(p1[idx]);
            float2 f2 = __half22float2(p2[idx]);
            float2 f3 = __half22float2(p3[idx]);
            float ax = acc[r * ACCS + 2 * l], ay = acc[r * ACCS + 2 * l + 1];
            float ox = fmaf(4.0f, f1.x, fmaf(5.0f, f2.x, fmaf(3.0f, f3.x, ax)));
            float oy = fmaf(4.0f, f1.y, fmaf(5.0f, f2.y, fmaf(3.0f, f3.y, ay)));
            out[idx] = make_float2(ox, oy);
        }
    }
}

extern "C" void kernel_launch(void* const* d_in, const int* in_sizes, int n_in,
                              void* d_out, int out_size, void* d_ws, size_t ws_size,
                              hipStream_t stream) {
    const float* x    = (const float*)d_in[0];
    const int*   rows = (const int*)d_in[1];
    const int*   cols = (const int*)d_in[2];
    const float* vals = (const float*)d_in[3];
    float2* out = (float2*)d_out;
    const int D = 64;
    const int N = in_sizes[0] / D;      // 200000
    const int nnz = in_sizes[1];        // 6400000
    const int NB = (N + DELTA - 1) / DELTA;   // 1563

    char* ws = (char*)d_ws;
    size_t off = 0;
    auto alloc = [&](size_t bytes) -> void* {
        void* p = ws + off;
        off = (off + bytes + 255) & ~(size_t)255;
        return p;
    };
    int*     fill     = (int*)alloc((size_t)MAXB * 4);
    int*     csr_base = (int*)alloc((size_t)(MAXB + 1) * 4);
    u64*     slab     = (u64*)alloc((size_t)NB * CAP * 8);  // 64 MB
    u64*     edges    = (u64*)alloc((size_t)nnz * 8);       // 51 MB
    __half2* B0 = (__half2*)alloc((size_t)N * D * 2);       // h, later p3
    __half2* B1 = (__half2*)alloc((size_t)N * D * 2);       // p1
    __half2* B2 = (__half2*)alloc((size_t)N * D * 2);       // p2
    (void)ws_size; (void)n_in; (void)out_size;

    hipMemsetAsync(fill, 0, (size_t)MAXB * 4, stream);

    const int rblocks = (N + 7) / 8;   // half-wave per row, 8 rows / 256-thr block
    compute_h_kernel<<<rblocks, 256, 0, stream>>>(x, B0, N);

    int pa_blocks = (nnz + PA_CHUNK - 1) / PA_CHUNK;   // 782
    pass_a_kernel<<<pa_blocks, 256, 0, stream>>>(rows, cols, vals, fill, slab, nnz, NB);
    bucket_scan_kernel<<<1, 256, 0, stream>>>(fill, csr_base, NB, nnz);
    pass_b_kernel<<<NB, 256, 0, stream>>>(fill, slab, csr_base, edges);

    // p1 = A h; p2 = A p1; p3 = A p2; out = 4p1 + 5p2 + 3p3 + A p3
    spmm_acc_kernel<<<NB, 256, 0, stream>>>(csr_base, edges, B0, B1, N);
    spmm_acc_kernel<<<NB, 256, 0, stream>>>(csr_base, edges, B1, B2, N);
    spmm_acc_kernel<<<NB, 256, 0, stream>>>(csr_base, edges, B2, B0, N);
    spmm_acc_final_kernel<<<NB, 256, 0, stream>>>(csr_base, edges, B1, B2, B0, out, N);
}

// Round 2
// 1736.787 us; speedup vs baseline: 5.6190x; 5.6190x over previous
//
#include <hip/hip_runtime.h>
#include <hip/hip_fp16.h>

#define SCAN_T 256
#define DELTA 512          // rows per bucket
#define LOG_DELTA 9
#define CAP 20480          // slab capacity per bucket (mean 16384, +32 sigma)
#define PA_CHUNK 8192      // edges per pass-A block
#define MAXB 512           // >= number of buckets (391)
#define NPH 32             // col phases (col>>13 -> 0..24 for N=200000)
#define NPH_USED 25
#define PHSHIFT 13

typedef unsigned long long u64;

// ---------------- logmap0 on the hyperboloid (c = 1), fp16 output ----------
// half-wave (32 lanes) per row; lane l owns dims (2l, 2l+1)
__global__ void compute_h_kernel(const float* __restrict__ x, __half2* __restrict__ h, int N) {
    int hw = (blockIdx.x * blockDim.x + threadIdx.x) >> 5;
    if (hw >= N) return;
    int l = threadIdx.x & 31;
    const float2* x2 = (const float2*)x;
    float2 v = x2[hw * 32 + l];
    float y2 = (l == 0) ? v.y * v.y : v.x * v.x + v.y * v.y;
    #pragma unroll
    for (int m = 16; m >= 1; m >>= 1) y2 += __shfl_xor(y2, m, 32);
    float x0 = __shfl(v.x, 0, 32);
    float ynorm = fmaxf(sqrtf(y2), 1e-15f);
    float theta = fmaxf(x0, 1.0f + 1e-7f);
    float alpha = acoshf(theta) / ynorm;
    float2 r = (l == 0) ? make_float2(0.0f, v.y * alpha)
                        : make_float2(v.x * alpha, v.y * alpha);
    h[hw * 32 + l] = __float22half2_rn(r);
}

__device__ __forceinline__ int block_incl_scan(int x) { // 256 threads
    __shared__ int sh[SCAN_T];
    int t = threadIdx.x;
    sh[t] = x; __syncthreads();
    for (int ofs = 1; ofs < SCAN_T; ofs <<= 1) {
        int y = (t >= ofs) ? sh[t - ofs] : 0;
        __syncthreads();
        x += y; sh[t] = x;
        __syncthreads();
    }
    return x;
}

// ---------------- Pass A: bin edges into row-buckets, block-private runs ----
// slab slot: [63:50]=local row (9b), [49:32]=col (18b), [31:0]=val f32 bits
__global__ void pass_a_kernel(const int* __restrict__ rows, const int* __restrict__ cols,
                              const float* __restrict__ vals, int* __restrict__ fill,
                              u64* __restrict__ slab, int nnz, int NB) {
    __shared__ int cnt[MAXB];
    __shared__ int cur[MAXB];
    int t = threadIdx.x;
    int start = blockIdx.x * PA_CHUNK;
    int end = min(start + PA_CHUNK, nnz);
    for (int i = t; i < NB; i += 256) cnt[i] = 0;
    __syncthreads();
    for (int e = start + t; e < end; e += 256)
        atomicAdd(&cnt[rows[e] >> LOG_DELTA], 1);
    __syncthreads();
    for (int i = t; i < NB; i += 256) {
        int c = cnt[i];
        cur[i] = (c > 0) ? atomicAdd(&fill[i], c) : 0;
    }
    __syncthreads();
    for (int e = start + t; e < end; e += 256) {
        int r = rows[e];
        int bkt = r >> LOG_DELTA;
        int lr = r & (DELTA - 1);
        int pos = atomicAdd(&cur[bkt], 1);
        if (pos < CAP) {
            u64 hi = ((u64)(((unsigned)lr << 18) | (unsigned)cols[e])) << 32;
            slab[(size_t)bkt * CAP + pos] = hi | (u64)__float_as_uint(vals[e]);
        }
    }
}

// ---------------- bucket-count exclusive scan (one block) ------------------
__global__ void bucket_scan_kernel(const int* __restrict__ fill, int* __restrict__ csr_base,
                                   int* __restrict__ row_ptr, int NB, int N, int nnz) {
    int t = threadIdx.x;
    int a0 = (2 * t < NB) ? fill[2 * t] : 0;
    int a1 = (2 * t + 1 < NB) ? fill[2 * t + 1] : 0;
    int s = a0 + a1;
    int incl = block_incl_scan(s);
    int excl = incl - s;
    if (2 * t < NB) csr_base[2 * t] = excl;
    if (2 * t + 1 < NB) csr_base[2 * t + 1] = excl + a0;
    if (t == 0) row_ptr[N] = nnz;
}

// ---------------- Pass B: per-bucket (lrow, col-phase) count-sort ----------
// Sorts each bucket's edges by (lrow, col>>PHSHIFT) so every row's edge list
// sweeps col space monotonically. Emits row_ptr AND the per-(row,phase) start
// offsets (pptr) so spmm blocks can enter a row's sweep at any phase.
// final edge: [63:32]=val f32 bits, [31:0]=col
__global__ void pass_b_kernel(const int* __restrict__ fill, const u64* __restrict__ slab,
                              const int* __restrict__ csr_base, u64* __restrict__ edges,
                              int* __restrict__ row_ptr, int* __restrict__ pptr, int N) {
    __shared__ int bins[DELTA * NPH];   // 64 KB
    int b = blockIdx.x;
    int t = threadIdx.x;
    for (int i = t; i < DELTA * NPH; i += 256) bins[i] = 0;
    __syncthreads();
    int m = fill[b];
    if (m > CAP) m = CAP;
    const u64* sl = slab + (size_t)b * CAP;
    for (int e = t; e < m; e += 256) {
        u64 u = sl[e];
        int lr = (int)(u >> 50);
        int col = (int)((u >> 32) & 0x3FFFFu);
        atomicAdd(&bins[lr * NPH + (col >> PHSHIFT)], 1);
    }
    __syncthreads();
    // exclusive scan over 16384 bins: thread t owns 64 consecutive bins
    int base = t * 64;
    int s = 0;
    #pragma unroll 4
    for (int k = 0; k < 64; ++k) s += bins[base + k];
    int incl = block_incl_scan(s);
    int run = incl - s;
    for (int k = 0; k < 64; ++k) { int c = bins[base + k]; bins[base + k] = run; run += c; }
    __syncthreads();
    int cb = csr_base[b];
    int base_row = b * DELTA;
    for (int lr = t; lr < DELTA; lr += 256) {
        int row = base_row + lr;
        if (row < N) row_ptr[row] = cb + bins[lr * NPH];
    }
    // persist per-(row,phase) starts: contiguous coalesced 64 KB store
    for (int i = t; i < DELTA * NPH; i += 256) {
        int row = base_row + (i >> 5);
        if (row < N) pptr[(size_t)base_row * NPH + i] = cb + bins[i];
    }
    __syncthreads();
    for (int e = t; e < m; e += 256) {
        u64 u = sl[e];
        int lr = (int)(u >> 50);
        unsigned col = (unsigned)(u >> 32) & 0x3FFFFu;
        unsigned vb = (unsigned)u;
        int pos = cb + atomicAdd(&bins[lr * NPH + (int)(col >> PHSHIFT)], 1);
        edges[pos] = ((u64)vb << 32) | col;
    }
}

// ---------------- CSR SpMM segment: 4-wide batches ------------------------
// 4 edges in flight keeps the instantaneous phase span ~3 phases (~3 MB band)
// while 24 waves/CU x 8 outstanding loads/wave still covers HBM latency.
__device__ __forceinline__ void spmm_seg(const u64* __restrict__ edges,
                                         const __half2* __restrict__ pin,
                                         int l, int j, int end,
                                         float& accx, float& accy) {
    for (; j + 4 <= end; j += 4) {
        u64 e0 = __builtin_nontemporal_load(&edges[j]);
        u64 e1 = __builtin_nontemporal_load(&edges[j + 1]);
        u64 e2 = __builtin_nontemporal_load(&edges[j + 2]);
        u64 e3 = __builtin_nontemporal_load(&edges[j + 3]);
        float2 f0 = __half22float2(pin[(int)(e0 & 0xFFFFFFFFu) * 32 + l]);
        float2 f1 = __half22float2(pin[(int)(e1 & 0xFFFFFFFFu) * 32 + l]);
        float2 f2 = __half22float2(pin[(int)(e2 & 0xFFFFFFFFu) * 32 + l]);
        float2 f3 = __half22float2(pin[(int)(e3 & 0xFFFFFFFFu) * 32 + l]);
        float v0 = __int_as_float((int)(e0 >> 32)), v1 = __int_as_float((int)(e1 >> 32));
        float v2 = __int_as_float((int)(e2 >> 32)), v3 = __int_as_float((int)(e3 >> 32));
        accx = fmaf(v0, f0.x, accx); accy = fmaf(v0, f0.y, accy);
        accx = fmaf(v1, f1.x, accx); accy = fmaf(v1, f1.y, accy);
        accx = fmaf(v2, f2.x, accx); accy = fmaf(v2, f2.y, accy);
        accx = fmaf(v3, f3.x, accx); accy = fmaf(v3, f3.y, accy);
    }
    for (; j < end; ++j) {
        u64 e = __builtin_nontemporal_load(&edges[j]);
        float2 f = __half22float2(pin[(int)(e & 0xFFFFFFFFu) * 32 + l]);
        float v = __int_as_float((int)(e >> 32));
        accx = fmaf(v, f.x, accx); accy = fmaf(v, f.y, accy);
    }
}

// block ticket -> global sweep phase; each row starts its (phase-sorted) edge
// list at that phase and wraps cyclically. Newly launched blocks join the
// moving column band where it currently is.
__device__ __forceinline__ int sweep_phase(unsigned* clk, int nb) {
    __shared__ int sph;
    if (threadIdx.x == 0) {
        unsigned g = atomicAdd(clk, 1u);
        sph = (int)(((g % (unsigned)nb) * (unsigned)NPH_USED) / (unsigned)nb);
    }
    __syncthreads();
    return sph;
}

__global__ void spmm_kernel(const int* __restrict__ row_ptr, const int* __restrict__ pptr,
                            const u64* __restrict__ edges, const __half2* __restrict__ pin,
                            __half2* __restrict__ pout, int N, int nb, unsigned* clk) {
    int sph = sweep_phase(clk, nb);
    int hw = (blockIdx.x * blockDim.x + threadIdx.x) >> 5;
    if (hw >= N) return;
    int l = threadIdx.x & 31;
    int start = row_ptr[hw];
    int end = row_ptr[hw + 1];
    int j0 = pptr[(size_t)hw * NPH + sph];
    float accx = 0.0f, accy = 0.0f;
    spmm_seg(edges, pin, l, j0, end, accx, accy);
    spmm_seg(edges, pin, l, start, j0, accx, accy);
    pout[hw * 32 + l] = __float22half2_rn(make_float2(accx, accy));
}

// final: acc = A*p3 (=p4);  out = 4*p1 + 5*p2 + 3*p3 + acc
__global__ void spmm_final_kernel(const int* __restrict__ row_ptr, const int* __restrict__ pptr,
                                  const u64* __restrict__ edges,
                                  const __half2* __restrict__ p1, const __half2* __restrict__ p2,
                                  const __half2* __restrict__ p3, float2* __restrict__ out,
                                  int N, int nb, unsigned* clk) {
    int sph = sweep_phase(clk, nb);
    int hw = (blockIdx.x * blockDim.x + threadIdx.x) >> 5;
    if (hw >= N) return;
    int l = threadIdx.x & 31;
    int start = row_ptr[hw];
    int end = row_ptr[hw + 1];
    int j0 = pptr[(size_t)hw * NPH + sph];
    float accx = 0.0f, accy = 0.0f;
    spmm_seg(edges, p3, l, j0, end, accx, accy);
    spmm_seg(edges, p3, l, start, j0, accx, accy);
    int idx = hw * 32 + l;
    float2 f1 = __half22float2(p1[idx]);
    float2 f2 = __half22float2(p2[idx]);
    float2 f3 = __half22float2(p3[idx]);
    float ox = fmaf(4.0f, f1.x, fmaf(5.0f, f2.x, fmaf(3.0f, f3.x, accx)));
    float oy = fmaf(4.0f, f1.y, fmaf(5.0f, f2.y, fmaf(3.0f, f3.y, accy)));
    out[idx] = make_float2(ox, oy);
}

extern "C" void kernel_launch(void* const* d_in, const int* in_sizes, int n_in,
                              void* d_out, int out_size, void* d_ws, size_t ws_size,
                              hipStream_t stream) {
    const float* x    = (const float*)d_in[0];
    const int*   rows = (const int*)d_in[1];
    const int*   cols = (const int*)d_in[2];
    const float* vals = (const float*)d_in[3];
    float2* out = (float2*)d_out;
    const int D = 64;
    const int N = in_sizes[0] / D;      // 200000
    const int nnz = in_sizes[1];        // 6400000
    const int NB = (N + DELTA - 1) / DELTA;   // 391

    char* ws = (char*)d_ws;
    size_t off = 0;
    auto alloc = [&](size_t bytes) -> void* {
        void* p = ws + off;
        off = (off + bytes + 255) & ~(size_t)255;
        return p;
    };
    int*      fill     = (int*)alloc((size_t)MAXB * 4);
    int*      csr_base = (int*)alloc((size_t)MAXB * 4);
    unsigned* clk      = (unsigned*)alloc(256);
    int*      row_ptr  = (int*)alloc((size_t)(N + 1) * 4);
    int*      pptr     = (int*)alloc((size_t)NB * DELTA * NPH * 4);  // 25.6 MB
    u64*      slab     = (u64*)alloc((size_t)NB * CAP * 8);  // 64 MB
    u64*      edges    = (u64*)alloc((size_t)nnz * 8);       // 51 MB
    __half2*  B0 = (__half2*)alloc((size_t)N * D * 2);       // h, later p3
    __half2*  B1 = (__half2*)alloc((size_t)N * D * 2);       // p1
    __half2*  B2 = (__half2*)alloc((size_t)N * D * 2);       // p2
    (void)ws_size; (void)n_in; (void)out_size;

    hipMemsetAsync(fill, 0, (size_t)MAXB * 4, stream);
    hipMemsetAsync(clk, 0, 4, stream);

    const int rblocks = (N + 7) / 8;   // half-wave per row, 8 rows / 256-thr block
    compute_h_kernel<<<rblocks, 256, 0, stream>>>(x, B0, N);

    int pa_blocks = (nnz + PA_CHUNK - 1) / PA_CHUNK;   // 782
    pass_a_kernel<<<pa_blocks, 256, 0, stream>>>(rows, cols, vals, fill, slab, nnz, NB);
    bucket_scan_kernel<<<1, 256, 0, stream>>>(fill, csr_base, row_ptr, NB, N, nnz);
    pass_b_kernel<<<NB, 256, 0, stream>>>(fill, slab, csr_base, edges, row_ptr, pptr, N);

    // p1 = A h; p2 = A p1; p3 = A p2; out = 4p1 + 5p2 + 3p3 + A p3
    spmm_kernel<<<rblocks, 256, 0, stream>>>(row_ptr, pptr, edges, B0, B1, N, rblocks, clk);
    spmm_kernel<<<rblocks, 256, 0, stream>>>(row_ptr, pptr, edges, B1, B2, N, rblocks, clk);
    spmm_kernel<<<rblocks, 256, 0, stream>>>(row_ptr, pptr, edges, B2, B0, N, rblocks, clk);
    spmm_final_kernel<<<rblocks, 256, 0, stream>>>(row_ptr, pptr, edges, B1, B2, B0, out, N, rblocks, clk);
}

// Round 3
// 1008.037 us; speedup vs baseline: 9.6812x; 1.7229x over previous
//
#include <hip/hip_runtime.h>
#include <hip/hip_fp16.h>

#define SCAN_T 256
#define DELTA 512          // rows per bucket
#define LOG_DELTA 9
#define CAP 20480          // slab capacity per bucket (mean 16384, +32 sigma)
#define PA_CHUNK 8192      // edges per pass-A block
#define MAXB 512           // >= number of buckets (391)
#define NPH 32             // col phases (col>>13 -> 0..24 for N=200000)
#define PHSHIFT 13
#define SPMM_BLOCKS 2048   // 8 blocks/CU x 256 CUs: exactly-resident persistent grid

typedef unsigned long long u64;

// ---------------- logmap0 on the hyperboloid (c = 1), fp16 output ----------
// half-wave (32 lanes) per row; lane l owns dims (2l, 2l+1)
__global__ void compute_h_kernel(const float* __restrict__ x, __half2* __restrict__ h, int N) {
    int hw = (blockIdx.x * blockDim.x + threadIdx.x) >> 5;
    if (hw >= N) return;
    int l = threadIdx.x & 31;
    const float2* x2 = (const float2*)x;
    float2 v = x2[hw * 32 + l];
    float y2 = (l == 0) ? v.y * v.y : v.x * v.x + v.y * v.y;
    #pragma unroll
    for (int m = 16; m >= 1; m >>= 1) y2 += __shfl_xor(y2, m, 32);
    float x0 = __shfl(v.x, 0, 32);
    float ynorm = fmaxf(sqrtf(y2), 1e-15f);
    float theta = fmaxf(x0, 1.0f + 1e-7f);
    float alpha = acoshf(theta) / ynorm;
    float2 r = (l == 0) ? make_float2(0.0f, v.y * alpha)
                        : make_float2(v.x * alpha, v.y * alpha);
    h[hw * 32 + l] = __float22half2_rn(r);
}

__device__ __forceinline__ int block_incl_scan(int x) { // 256 threads
    __shared__ int sh[SCAN_T];
    int t = threadIdx.x;
    sh[t] = x; __syncthreads();
    for (int ofs = 1; ofs < SCAN_T; ofs <<= 1) {
        int y = (t >= ofs) ? sh[t - ofs] : 0;
        __syncthreads();
        x += y; sh[t] = x;
        __syncthreads();
    }
    return x;
}

// ---------------- Pass A: bin edges into row-buckets, block-private runs ----
// slab slot: [63:50]=local row (9b), [49:32]=col (18b), [31:0]=val f32 bits
__global__ void pass_a_kernel(const int* __restrict__ rows, const int* __restrict__ cols,
                              const float* __restrict__ vals, int* __restrict__ fill,
                              u64* __restrict__ slab, int nnz, int NB) {
    __shared__ int cnt[MAXB];
    __shared__ int cur[MAXB];
    int t = threadIdx.x;
    int start = blockIdx.x * PA_CHUNK;
    int end = min(start + PA_CHUNK, nnz);
    for (int i = t; i < NB; i += 256) cnt[i] = 0;
    __syncthreads();
    for (int e = start + t; e < end; e += 256)
        atomicAdd(&cnt[rows[e] >> LOG_DELTA], 1);
    __syncthreads();
    for (int i = t; i < NB; i += 256) {
        int c = cnt[i];
        cur[i] = (c > 0) ? atomicAdd(&fill[i], c) : 0;
    }
    __syncthreads();
    for (int e = start + t; e < end; e += 256) {
        int r = rows[e];
        int bkt = r >> LOG_DELTA;
        int lr = r & (DELTA - 1);
        int pos = atomicAdd(&cur[bkt], 1);
        if (pos < CAP) {
            u64 hi = ((u64)(((unsigned)lr << 18) | (unsigned)cols[e])) << 32;
            slab[(size_t)bkt * CAP + pos] = hi | (u64)__float_as_uint(vals[e]);
        }
    }
}

// ---------------- bucket-count exclusive scan (one block) ------------------
__global__ void bucket_scan_kernel(const int* __restrict__ fill, int* __restrict__ csr_base,
                                   int* __restrict__ row_ptr, int NB, int N, int nnz) {
    int t = threadIdx.x;
    int a0 = (2 * t < NB) ? fill[2 * t] : 0;
    int a1 = (2 * t + 1 < NB) ? fill[2 * t + 1] : 0;
    int s = a0 + a1;
    int incl = block_incl_scan(s);
    int excl = incl - s;
    if (2 * t < NB) csr_base[2 * t] = excl;
    if (2 * t + 1 < NB) csr_base[2 * t + 1] = excl + a0;
    if (t == 0) row_ptr[N] = nnz;
}

// ---------------- Pass B: per-bucket (lrow, col-phase) count-sort ----------
// Sorts each bucket's edges by (lrow, col>>PHSHIFT) so every row's edge list
// sweeps col space monotonically -> concurrent gathers cluster in an L2-sized
// band. Also emits row_ptr. final edge: [63:32]=val f32 bits, [31:0]=col
__global__ void pass_b_kernel(const int* __restrict__ fill, const u64* __restrict__ slab,
                              const int* __restrict__ csr_base, u64* __restrict__ edges,
                              int* __restrict__ row_ptr, int N) {
    __shared__ int bins[DELTA * NPH];   // 64 KB
    int b = blockIdx.x;
    int t = threadIdx.x;
    for (int i = t; i < DELTA * NPH; i += 256) bins[i] = 0;
    __syncthreads();
    int m = fill[b];
    if (m > CAP) m = CAP;
    const u64* sl = slab + (size_t)b * CAP;
    for (int e = t; e < m; e += 256) {
        u64 u = sl[e];
        int lr = (int)(u >> 50);
        int col = (int)((u >> 32) & 0x3FFFFu);
        atomicAdd(&bins[lr * NPH + (col >> PHSHIFT)], 1);
    }
    __syncthreads();
    // exclusive scan over 16384 bins: thread t owns 64 consecutive bins
    int base = t * 64;
    int s = 0;
    #pragma unroll 4
    for (int k = 0; k < 64; ++k) s += bins[base + k];
    int incl = block_incl_scan(s);
    int run = incl - s;
    for (int k = 0; k < 64; ++k) { int c = bins[base + k]; bins[base + k] = run; run += c; }
    __syncthreads();
    int cb = csr_base[b];
    int base_row = b * DELTA;
    for (int lr = t; lr < DELTA; lr += 256) {
        int row = base_row + lr;
        if (row < N) row_ptr[row] = cb + bins[lr * NPH];
    }
    __syncthreads();
    for (int e = t; e < m; e += 256) {
        u64 u = sl[e];
        int lr = (int)(u >> 50);
        unsigned col = (unsigned)(u >> 32) & 0x3FFFFu;
        unsigned vb = (unsigned)u;
        int pos = cb + atomicAdd(&bins[lr * NPH + (int)(col >> PHSHIFT)], 1);
        edges[pos] = ((u64)vb << 32) | col;
    }
}

// ---------------- CSR SpMM: pout(fp16) = A * pin(fp16) ---------------------
// half-wave (32 lanes) per row; lane l owns dims (2l, 2l+1)
__device__ __forceinline__ void spmm_row(const int* __restrict__ row_ptr,
                                         const u64* __restrict__ edges,
                                         const __half2* __restrict__ pin,
                                         int hw, int l, float& accx, float& accy) {
    int j = row_ptr[hw];
    int end = row_ptr[hw + 1];
    accx = 0.0f; accy = 0.0f;
    for (; j + 8 <= end; j += 8) {
        u64 e0 = __builtin_nontemporal_load(&edges[j]);
        u64 e1 = __builtin_nontemporal_load(&edges[j + 1]);
        u64 e2 = __builtin_nontemporal_load(&edges[j + 2]);
        u64 e3 = __builtin_nontemporal_load(&edges[j + 3]);
        u64 e4 = __builtin_nontemporal_load(&edges[j + 4]);
        u64 e5 = __builtin_nontemporal_load(&edges[j + 5]);
        u64 e6 = __builtin_nontemporal_load(&edges[j + 6]);
        u64 e7 = __builtin_nontemporal_load(&edges[j + 7]);
        float2 f0 = __half22float2(pin[(int)(e0 & 0xFFFFFFFFu) * 32 + l]);
        float2 f1 = __half22float2(pin[(int)(e1 & 0xFFFFFFFFu) * 32 + l]);
        float2 f2 = __half22float2(pin[(int)(e2 & 0xFFFFFFFFu) * 32 + l]);
        float2 f3 = __half22float2(pin[(int)(e3 & 0xFFFFFFFFu) * 32 + l]);
        float2 f4 = __half22float2(pin[(int)(e4 & 0xFFFFFFFFu) * 32 + l]);
        float2 f5 = __half22float2(pin[(int)(e5 & 0xFFFFFFFFu) * 32 + l]);
        float2 f6 = __half22float2(pin[(int)(e6 & 0xFFFFFFFFu) * 32 + l]);
        float2 f7 = __half22float2(pin[(int)(e7 & 0xFFFFFFFFu) * 32 + l]);
        float v0 = __int_as_float((int)(e0 >> 32)), v1 = __int_as_float((int)(e1 >> 32));
        float v2 = __int_as_float((int)(e2 >> 32)), v3 = __int_as_float((int)(e3 >> 32));
        float v4 = __int_as_float((int)(e4 >> 32)), v5 = __int_as_float((int)(e5 >> 32));
        float v6 = __int_as_float((int)(e6 >> 32)), v7 = __int_as_float((int)(e7 >> 32));
        accx = fmaf(v0, f0.x, accx); accy = fmaf(v0, f0.y, accy);
        accx = fmaf(v1, f1.x, accx); accy = fmaf(v1, f1.y, accy);
        accx = fmaf(v2, f2.x, accx); accy = fmaf(v2, f2.y, accy);
        accx = fmaf(v3, f3.x, accx); accy = fmaf(v3, f3.y, accy);
        accx = fmaf(v4, f4.x, accx); accy = fmaf(v4, f4.y, accy);
        accx = fmaf(v5, f5.x, accx); accy = fmaf(v5, f5.y, accy);
        accx = fmaf(v6, f6.x, accx); accy = fmaf(v6, f6.y, accy);
        accx = fmaf(v7, f7.x, accx); accy = fmaf(v7, f7.y, accy);
    }
    for (; j < end; ++j) {
        u64 e = __builtin_nontemporal_load(&edges[j]);
        float2 f = __half22float2(pin[(int)(e & 0xFFFFFFFFu) * 32 + l]);
        float v = __int_as_float((int)(e >> 32));
        accx = fmaf(v, f.x, accx); accy = fmaf(v, f.y, accy);
    }
}

// Persistent grid: SPMM_BLOCKS blocks (8/CU, exactly resident) grid-stride
// over 8-row chunks. All blocks start together and each chunk is one full
// phase-0..24 column sweep of ~equal work, so phase-0 restarts stay chip-wide
// synchronized -> co-resident gathers form a moving L2-resident column band
// (self-correcting: leaders hit cold lines and slow, laggards hit warm ones).
__global__ __launch_bounds__(256)
void spmm_kernel(const int* __restrict__ row_ptr, const u64* __restrict__ edges,
                 const __half2* __restrict__ pin, __half2* __restrict__ pout, int N) {
    int l = threadIdx.x & 31;
    int sub = threadIdx.x >> 5;           // 0..7: half-wave index in block
    int nchunk = (N + 7) >> 3;
    for (int c = blockIdx.x; c < nchunk; c += gridDim.x) {
        int hw = c * 8 + sub;
        if (hw >= N) continue;
        float accx, accy;
        spmm_row(row_ptr, edges, pin, hw, l, accx, accy);
        pout[hw * 32 + l] = __float22half2_rn(make_float2(accx, accy));
    }
}

// final: acc = A*p3 (=p4);  out = 4*p1 + 5*p2 + 3*p3 + acc
__global__ __launch_bounds__(256)
void spmm_final_kernel(const int* __restrict__ row_ptr, const u64* __restrict__ edges,
                       const __half2* __restrict__ p1, const __half2* __restrict__ p2,
                       const __half2* __restrict__ p3, float2* __restrict__ out, int N) {
    int l = threadIdx.x & 31;
    int sub = threadIdx.x >> 5;
    int nchunk = (N + 7) >> 3;
    for (int c = blockIdx.x; c < nchunk; c += gridDim.x) {
        int hw = c * 8 + sub;
        if (hw >= N) continue;
        float accx, accy;
        spmm_row(row_ptr, edges, p3, hw, l, accx, accy);
        int idx = hw * 32 + l;
        float2 f1 = __half22float2(p1[idx]);
        float2 f2 = __half22float2(p2[idx]);
        float2 f3 = __half22float2(p3[idx]);
        float ox = fmaf(4.0f, f1.x, fmaf(5.0f, f2.x, fmaf(3.0f, f3.x, accx)));
        float oy = fmaf(4.0f, f1.y, fmaf(5.0f, f2.y, fmaf(3.0f, f3.y, accy)));
        out[idx] = make_float2(ox, oy);
    }
}

extern "C" void kernel_launch(void* const* d_in, const int* in_sizes, int n_in,
                              void* d_out, int out_size, void* d_ws, size_t ws_size,
                              hipStream_t stream) {
    const float* x    = (const float*)d_in[0];
    const int*   rows = (const int*)d_in[1];
    const int*   cols = (const int*)d_in[2];
    const float* vals = (const float*)d_in[3];
    float2* out = (float2*)d_out;
    const int D = 64;
    const int N = in_sizes[0] / D;      // 200000
    const int nnz = in_sizes[1];        // 6400000
    const int NB = (N + DELTA - 1) / DELTA;   // 391

    char* ws = (char*)d_ws;
    size_t off = 0;
    auto alloc = [&](size_t bytes) -> void* {
        void* p = ws + off;
        off = (off + bytes + 255) & ~(size_t)255;
        return p;
    };
    int*     fill     = (int*)alloc((size_t)MAXB * 4);
    int*     csr_base = (int*)alloc((size_t)MAXB * 4);
    int*     row_ptr  = (int*)alloc((size_t)(N + 1) * 4);
    u64*     slab     = (u64*)alloc((size_t)NB * CAP * 8);  // 64 MB
    u64*     edges    = (u64*)alloc((size_t)nnz * 8);       // 51 MB
    __half2* B0 = (__half2*)alloc((size_t)N * D * 2);       // h, later p3
    __half2* B1 = (__half2*)alloc((size_t)N * D * 2);       // p1
    __half2* B2 = (__half2*)alloc((size_t)N * D * 2);       // p2
    (void)ws_size; (void)n_in; (void)out_size;

    hipMemsetAsync(fill, 0, (size_t)MAXB * 4, stream);

    const int rblocks = (N + 7) / 8;   // half-wave per row, 8 rows / 256-thr block
    compute_h_kernel<<<rblocks, 256, 0, stream>>>(x, B0, N);

    int pa_blocks = (nnz + PA_CHUNK - 1) / PA_CHUNK;   // 782
    pass_a_kernel<<<pa_blocks, 256, 0, stream>>>(rows, cols, vals, fill, slab, nnz, NB);
    bucket_scan_kernel<<<1, 256, 0, stream>>>(fill, csr_base, row_ptr, NB, N, nnz);
    pass_b_kernel<<<NB, 256, 0, stream>>>(fill, slab, csr_base, edges, row_ptr, N);

    // p1 = A h; p2 = A p1; p3 = A p2; out = 4p1 + 5p2 + 3p3 + A p3
    spmm_kernel<<<SPMM_BLOCKS, 256, 0, stream>>>(row_ptr, edges, B0, B1, N);
    spmm_kernel<<<SPMM_BLOCKS, 256, 0, stream>>>(row_ptr, edges, B1, B2, N);
    spmm_kernel<<<SPMM_BLOCKS, 256, 0, stream>>>(row_ptr, edges, B2, B0, N);
    spmm_final_kernel<<<SPMM_BLOCKS, 256, 0, stream>>>(row_ptr, edges, B1, B2, B0, out, N);
}